// Round 5
// baseline (127.065 us; speedup 1.0000x reference)
//
#include <hip/hip_runtime.h>
#include <hip/hip_bf16.h>

// B=128, CIN=3, H=W=32, C1=64, C2=256, NUM_CLASSES=1000
// K_CONV=48, K_FC=12451 >= 48*256 => FC reduces exactly to the 48 selected
// channels' pooled features (non-selected channels are exactly zero).
// Slot order = gate-score rank order (top_k order); FC sum is order-invariant.

#define NSEL 48
#define NCLS 1000

__device__ __forceinline__ unsigned short f2bf(float x) {
  unsigned u = __builtin_bit_cast(unsigned, x);
  u += 0x7fffu + ((u >> 16) & 1u);  // RNE (finite inputs)
  return (unsigned short)(u >> 16);
}

__device__ __forceinline__ void gl_lds16(const void* g, void* l) {
  __builtin_amdgcn_global_load_lds(
      (const __attribute__((address_space(1))) void*)g,
      (__attribute__((address_space(3))) void*)l, 16, 0, 0);
}

using sh8 = __attribute__((ext_vector_type(8))) short;
using f4  = __attribute__((ext_vector_type(4))) float;

// ---------------- K1: conv1 + ReLU -> x1 bf16 [b][pix][64ic]; |.| partial sums ----
__global__ __launch_bounds__(256) void k1_conv1(
    const float* __restrict__ x0, const float* __restrict__ w1,
    const float* __restrict__ b1, unsigned short* __restrict__ x1,
    float* __restrict__ part2) {
  const int b = blockIdx.x, quarter = blockIdx.y;
  const int t = threadIdx.x;
  const int wv = t >> 6;
  __shared__ float xs[3 * 320];   // 3 ic x 10 rows x 32 cols
  __shared__ float wred[64 * 4];
  const int r0 = quarter * 8;

  for (int q = 0; q < 15; ++q) {  // 3840 floats
    const int id = q * 256 + t;
    const int ic = id / 320;
    const int rem = id - ic * 320;
    const int row = rem >> 5, col = rem & 31;
    const int gr = r0 - 1 + row;
    xs[id] = ((unsigned)gr < 32u)
                 ? x0[((size_t)b * 3 + ic) * 1024 + gr * 32 + col] : 0.f;
  }
  __syncthreads();

  const int lr = t >> 5, pc = t & 31;
  float win[3][3][3];
#pragma unroll
  for (int ic = 0; ic < 3; ++ic)
#pragma unroll
    for (int kr = 0; kr < 3; ++kr)
#pragma unroll
      for (int kc = 0; kc < 3; ++kc) {
        const int cc = pc - 1 + kc;
        win[ic][kr][kc] = ((unsigned)cc < 32u) ? xs[ic * 320 + (lr + kr) * 32 + cc] : 0.f;
      }

  unsigned pk[32];
#pragma unroll
  for (int oc = 0; oc < 64; ++oc) {
    float a = b1[oc];
#pragma unroll
    for (int ic = 0; ic < 3; ++ic)
#pragma unroll
      for (int kr = 0; kr < 3; ++kr)
#pragma unroll
        for (int kc = 0; kc < 3; ++kc)
          a += w1[oc * 27 + ic * 9 + kr * 3 + kc] * win[ic][kr][kc];
    const float v = a > 0.f ? a : 0.f;
    const unsigned bf = f2bf(v);
    if (oc & 1) pk[oc >> 1] |= bf << 16; else pk[oc >> 1] = bf;
    float rs = v;
    for (int off = 32; off > 0; off >>= 1) rs += __shfl_down(rs, off, 64);
    if ((t & 63) == 0) wred[oc * 4 + wv] = rs;
  }

  {
    int4* dst = reinterpret_cast<int4*>(x1) +
                ((size_t)b * 1024 + (r0 + lr) * 32 + pc) * 8;
    const int4* src = reinterpret_cast<const int4*>(pk);
#pragma unroll
    for (int j2 = 0; j2 < 8; ++j2) dst[j2] = src[j2];
  }
  __syncthreads();
  if (t < 64) {
    const float s = wred[t * 4] + wred[t * 4 + 1] + wred[t * 4 + 2] + wred[t * 4 + 3];
    part2[((size_t)quarter * 64 + t) * 128 + b] = s;
  }
}

// ---------------- K2: selection (redundant per block) + weight prep (block j) -----
// grid 48 blocks x 256 thr. part2 layout [quarter*64 + c][128 b].
__global__ __launch_bounds__(256) void k2_selprep(
    const float* __restrict__ part2, const float* __restrict__ gate_w,
    const float* __restrict__ w2, const float* __restrict__ b2,
    int* __restrict__ sel, unsigned short* __restrict__ w2t,
    float* __restrict__ b2s) {
  const int t = threadIdx.x;
  const int j = blockIdx.x;  // slot = rank
  __shared__ float red[64 * 33];
  __shared__ float sig[64];
  __shared__ float sc[256];
  __shared__ int pick;

  // Full coalesced reduction of part2 (32768 floats = 8192 float4).
  // float4 id f = q*256+t: row r = f>>5 = q*8 + (t>>5), col4 = t&31.
  // channel c = r&63 = (q&7)*8 + (t>>5); quarter = q>>3.
  float prt[8];
#pragma unroll
  for (int k = 0; k < 8; ++k) prt[k] = 0.f;
  const float4* pv = reinterpret_cast<const float4*>(part2);
#pragma unroll
  for (int q = 0; q < 32; ++q) {
    const float4 v = pv[q * 256 + t];
    prt[q & 7] += v.x + v.y + v.z + v.w;
  }
#pragma unroll
  for (int k = 0; k < 8; ++k) {
    const int c = k * 8 + (t >> 5);
    red[c * 33 + (t & 31)] = prt[k];
  }
  __syncthreads();
  if (t < 64) {
    float s = 0.f;
    for (int i = 0; i < 32; ++i) s += red[t * 33 + i];
    sig[t] = s * (1.0f / 131072.0f);
  }
  __syncthreads();

  {  // gate logits (softplus monotone -> rank by logits)
    float lg = 0.f;
#pragma unroll 8
    for (int i = 0; i < 64; ++i) lg += gate_w[t * 64 + i] * sig[i];
    sc[t] = lg;
  }
  __syncthreads();

  {  // rank = position in desc sort with index tiebreak (top_k order)
    const float v = sc[t];
    int r = 0;
    for (int i = 0; i < 256; ++i) {
      const float vi = sc[i];
      r += (vi > v) || (vi == v && i < t);
    }
    if (r == j) pick = t;
    if (j == 0 && r < NSEL) sel[r] = t;
  }
  __syncthreads();

  const int c = pick;
  if (t == 0) b2s[j] = b2[c];
  for (int id = t; id < 576; id += 256) {
    const float v = w2[(size_t)c * 576 + id];
    const int ic = id / 9;
    const int s = id - ic * 9;
    w2t[((size_t)s * 48 + j) * 64 + ic] = f2bf(v);
  }
}

// ---------------- K3: conv2 via 9-shift bf16 MFMA + bias + ReLU + maxpool ---------
__global__ __launch_bounds__(256) void k3_conv2(
    const unsigned short* __restrict__ x1, const unsigned short* __restrict__ w2t,
    const float* __restrict__ b2s, unsigned short* __restrict__ pooledt) {
  const int b = blockIdx.x, quarter = blockIdx.y;
  const int t = threadIdx.x;
  const int w = t >> 6, l = t & 63;
  const int q4 = l >> 4, ln15 = l & 15;
  __shared__ short xt[20480];  // 10 rows x 32 cols x 64 ic bf16, 16B-slot swizzled

  const int r0 = quarter * 8;

  for (int q = 0; q < 10; ++q) {
    const int S = (w * 10 + q) * 64 + l;
    const int pix = S >> 3, slot = S & 7;
    const int row = pix >> 5, col = pix & 31;
    int gr = r0 - 1 + row;
    gr = gr < 0 ? 0 : (gr > 31 ? 31 : gr);
    const unsigned short* gsrc =
        x1 + ((size_t)(b * 1024 + gr * 32 + col) * 64) + (slot ^ (pix & 7)) * 8;
    gl_lds16((const void*)gsrc, (void*)&xt[(w * 10 + q) * 512]);
  }
  __syncthreads();

  f4 acc[4][3];
  const f4 fz = {0.f, 0.f, 0.f, 0.f};
#pragma unroll
  for (int i = 0; i < 4; ++i)
#pragma unroll
    for (int nt = 0; nt < 3; ++nt) acc[i][nt] = fz;

  const int w4 = w * 4;
  const sh8 zz = {0, 0, 0, 0, 0, 0, 0, 0};

#pragma unroll
  for (int kh = 0; kh < 3; ++kh)
#pragma unroll
    for (int kw = 0; kw < 3; ++kw) {
      const int sh = kh * 3 + kw;
      sh8 bf[3][2];
#pragma unroll
      for (int nt = 0; nt < 3; ++nt)
#pragma unroll
        for (int ks = 0; ks < 2; ++ks)
          bf[nt][ks] = *reinterpret_cast<const sh8*>(
              w2t + ((size_t)(sh * 48 + nt * 16 + ln15) * 64 + ks * 32 + q4 * 8));
#pragma unroll
      for (int i = 0; i < 4; ++i) {
        const int mt = w4 + i;
        const int lsr = (mt >> 1) + kh;
        const int gsr = r0 + lsr - 1;
        if ((unsigned)gsr < 32u) {
          const int w_ = (mt & 1) * 16 + ln15;
          const int cc = w_ + kw - 1;
          const bool cv = (unsigned)cc < 32u;
          int p = lsr * 32 + cc;
          p = p < 0 ? 0 : (p > 319 ? 319 : p);
#pragma unroll
          for (int ks = 0; ks < 2; ++ks) {
            sh8 af = *reinterpret_cast<const sh8*>(
                &xt[p * 64 + (((ks << 2) | q4) ^ (p & 7)) * 8]);
            af = cv ? af : zz;
            acc[i][0] = __builtin_amdgcn_mfma_f32_16x16x32_bf16(af, bf[0][ks], acc[i][0], 0, 0, 0);
            acc[i][1] = __builtin_amdgcn_mfma_f32_16x16x32_bf16(af, bf[1][ks], acc[i][1], 0, 0, 0);
            acc[i][2] = __builtin_amdgcn_mfma_f32_16x16x32_bf16(af, bf[2][ks], acc[i][2], 0, 0, 0);
          }
        }
      }
    }

  __syncthreads();

  float bias[3];
#pragma unroll
  for (int nt = 0; nt < 3; ++nt) bias[nt] = b2s[nt * 16 + ln15];

  unsigned short* ps = reinterpret_cast<unsigned short*>(xt);
#pragma unroll
  for (int a = 0; a < 2; ++a) {
#pragma unroll
    for (int nt = 0; nt < 3; ++nt) {
      const f4 A = acc[a][nt], Bv = acc[a + 2][nt];
#pragma unroll
      for (int pr = 0; pr < 2; ++pr) {
        float m = fmaxf(fmaxf(A[pr * 2], A[pr * 2 + 1]),
                        fmaxf(Bv[pr * 2], Bv[pr * 2 + 1]));
        m = fmaxf(m + bias[nt], 0.f);
        const int pl = w * 16 + a * 8 + q4 * 2 + pr;
        ps[(nt * 16 + ln15) * 64 + pl] = f2bf(m);
      }
    }
  }
  __syncthreads();

  const int4* psv = reinterpret_cast<const int4*>(xt);
  int4* po = reinterpret_cast<int4*>(pooledt);
  for (int c = t; c < 384; c += 256) {
    const int j = c >> 3, sub = c & 7;
    po[(size_t)(j * 32 + quarter * 8 + sub) * 128 + b] = psv[c];
  }
}

// ---------------- K4: bf16 MFMA GEMM partials. BM=128, BN=32, Ksplit=16, depth-2 --
__global__ __launch_bounds__(256) void k4_fc(
    const unsigned short* __restrict__ pooledt, const float* __restrict__ fc_w,
    const int* __restrict__ sel, float* __restrict__ fcpart) {
  const int ntile = blockIdx.x;  // 0..31
  const int ks = blockIdx.y;     // 0..15 (K chunk = 768 = 3 channels)
  const int t = threadIdx.x;
  const int w = t >> 6, l = t & 63;

  __shared__ short Ab[2][8 * 129 * 8];  // [ko][m pad129][8]
  __shared__ short Bb[2][8 * 33 * 8];   // [ko][n pad33][8]

  f4 acc00 = {0.f, 0.f, 0.f, 0.f}, acc01 = acc00, acc10 = acc00, acc11 = acc00;

  int ch[3];
#pragma unroll
  for (int i = 0; i < 3; ++i)
    ch[i] = __builtin_amdgcn_readfirstlane(sel[ks * 3 + i]);

  const int n0 = ntile * 32;
  const int nrow = t >> 3, koct = t & 7;
  int ng = n0 + nrow; if (ng > 999) ng = 999;
  const float* wbase = fc_w + (size_t)ng * 65536 + koct * 8;

  const int4* pt = reinterpret_cast<const int4*>(pooledt);
  const int kb0 = ks * 96;

#define LOADA(tn, av)                                                     \
  {                                                                       \
    _Pragma("unroll") for (int it = 0; it < 4; ++it) {                    \
      const int s = it * 256 + t;                                         \
      av[it] = pt[(kb0 + (tn) * 8 + (s >> 7)) * 128 + (s & 127)];         \
    }                                                                     \
  }
#define LOADB(tn, b0, b1)                                                 \
  {                                                                       \
    const float* bp = wbase + ch[(tn) >> 2] * 256 + ((tn) & 3) * 64;      \
    b0 = *reinterpret_cast<const float4*>(bp);                            \
    b1 = *reinterpret_cast<const float4*>(bp + 4);                        \
  }
#define WRITE(buf, av, b0, b1)                                            \
  {                                                                       \
    _Pragma("unroll") for (int it = 0; it < 4; ++it) {                    \
      const int s = it * 256 + t;                                         \
      *reinterpret_cast<int4*>(&Ab[buf][((s >> 7) * 129 + (s & 127)) * 8]) = av[it]; \
    }                                                                     \
    int4 bw;                                                              \
    bw.x = f2bf(b0.x) | ((unsigned)f2bf(b0.y) << 16);                     \
    bw.y = f2bf(b0.z) | ((unsigned)f2bf(b0.w) << 16);                     \
    bw.z = f2bf(b1.x) | ((unsigned)f2bf(b1.y) << 16);                     \
    bw.w = f2bf(b1.z) | ((unsigned)f2bf(b1.w) << 16);                     \
    *reinterpret_cast<int4*>(&Bb[buf][(koct * 33 + nrow) * 8]) = bw;      \
  }
#define COMP(buf)                                                         \
  {                                                                       \
    _Pragma("unroll") for (int s2 = 0; s2 < 2; ++s2) {                    \
      const int kg = s2 * 4 + (l >> 4);                                   \
      const int m0 = w * 32 + (l & 15);                                   \
      sh8 a0 = *reinterpret_cast<const sh8*>(&Ab[buf][(kg * 129 + m0) * 8]);      \
      sh8 a1 = *reinterpret_cast<const sh8*>(&Ab[buf][(kg * 129 + m0 + 16) * 8]); \
      sh8 b0 = *reinterpret_cast<const sh8*>(&Bb[buf][(kg * 33 + (l & 15)) * 8]); \
      sh8 b1 = *reinterpret_cast<const sh8*>(&Bb[buf][(kg * 33 + 16 + (l & 15)) * 8]); \
      acc00 = __builtin_amdgcn_mfma_f32_16x16x32_bf16(a0, b0, acc00, 0, 0, 0); \
      acc01 = __builtin_amdgcn_mfma_f32_16x16x32_bf16(a0, b1, acc01, 0, 0, 0); \
      acc10 = __builtin_amdgcn_mfma_f32_16x16x32_bf16(a1, b0, acc10, 0, 0, 0); \
      acc11 = __builtin_amdgcn_mfma_f32_16x16x32_bf16(a1, b1, acc11, 0, 0, 0); \
    }                                                                     \
  }

  int4 avA[4], avB[4];
  float4 bA0, bA1, bB0, bB1;

  LOADA(0, avA); LOADB(0, bA0, bA1);
  LOADA(1, avB); LOADB(1, bB0, bB1);
  WRITE(0, avA, bA0, bA1);
  __syncthreads();

  for (int tt = 0; tt < 12; tt += 2) {
    if (tt + 2 < 12) { LOADA(tt + 2, avA); LOADB(tt + 2, bA0, bA1); }
    COMP(0);
    WRITE(1, avB, bB0, bB1);
    __syncthreads();
    if (tt + 3 < 12) { LOADA(tt + 3, avB); LOADB(tt + 3, bB0, bB1); }
    COMP(1);
    if (tt + 2 < 12) { WRITE(0, avA, bA0, bA1); }
    __syncthreads();
  }

  const int r0 = (l >> 4) * 4;
#pragma unroll
  for (int fm = 0; fm < 2; ++fm)
#pragma unroll
    for (int fn = 0; fn < 2; ++fn)
#pragma unroll
      for (int r = 0; r < 4; ++r) {
        const int m = w * 32 + fm * 16 + r0 + r;
        const int nc = n0 + fn * 16 + (l & 15);
        const f4 a = fm == 0 ? (fn == 0 ? acc00 : acc01) : (fn == 0 ? acc10 : acc11);
        fcpart[(((size_t)ks * 128 + m) << 10) + nc] = a[r];
      }
#undef LOADA
#undef LOADB
#undef WRITE
#undef COMP
}

// ---------------- K5: reduce K-split partials + bias ------------------------------
__global__ __launch_bounds__(256) void k5_reduce(
    const float* __restrict__ fcpart, const float* __restrict__ fc_b,
    float* __restrict__ out) {
  const int id = blockIdx.x * 256 + threadIdx.x;
  const int b = id / 1000;
  const int n = id - b * 1000;
  float s = fc_b[n];
#pragma unroll
  for (int ks = 0; ks < 16; ++ks)
    s += fcpart[(((size_t)ks * 128 + b) << 10) + n];
  out[id] = s;
}

extern "C" void kernel_launch(void* const* d_in, const int* in_sizes, int n_in,
                              void* d_out, int out_size, void* d_ws, size_t ws_size,
                              hipStream_t stream) {
  (void)in_sizes; (void)n_in; (void)out_size; (void)ws_size;
  const float* x0     = (const float*)d_in[0];
  const float* w1     = (const float*)d_in[1];
  const float* b1     = (const float*)d_in[2];
  const float* gate_w = (const float*)d_in[3];
  const float* w2     = (const float*)d_in[4];
  const float* b2     = (const float*)d_in[5];
  const float* fc_w   = (const float*)d_in[6];
  const float* fc_b   = (const float*)d_in[7];
  float* out = (float*)d_out;

  char* ws = (char*)d_ws;
  unsigned short* x1      = (unsigned short*)(ws);             // 16,777,216 B
  unsigned short* pooledt = (unsigned short*)(ws + 16777216);  //  3,145,728 B
  float*          part2   = (float*)(ws + 19922944);           //    131,072 B
  int*            sel     = (int*)  (ws + 20054016);           //        256 B
  unsigned short* w2t     = (unsigned short*)(ws + 20054272);  //     55,296 B
  float*          b2s     = (float*)(ws + 20109568);           //        768 B
  float*          fcpart  = (float*)(ws + 20110336);           //  8,388,608 B

  hipLaunchKernelGGL(k1_conv1, dim3(128, 4), dim3(256), 0, stream, x0, w1, b1, x1, part2);
  hipLaunchKernelGGL(k2_selprep, dim3(48), dim3(256), 0, stream, part2, gate_w, w2, b2, sel, w2t, b2s);
  hipLaunchKernelGGL(k3_conv2, dim3(128, 4), dim3(256), 0, stream, x1, w2t, b2s, pooledt);
  hipLaunchKernelGGL(k4_fc, dim3(32, 16), dim3(256), 0, stream, pooledt, fc_w, sel, fcpart);
  hipLaunchKernelGGL(k5_reduce, dim3(500), dim3(256), 0, stream, fcpart, fc_b, out);
}